// Round 2
// baseline (725.816 us; speedup 1.0000x reference)
//
#include <hip/hip_runtime.h>
#include <hip/hip_bf16.h>

#define N_NODES 50000
#define N_EDGES 300000
#define E_TOT   350000   /* edges + self loops */
#define N_GRAPHS 256
#define F_IN 78
#define H1 10
#define D1 780           /* H1*F_H1 */
#define F_OUT 128
#define NEG_SLOPE 0.2f
#define NB 196           /* ceil(50000/256) */

__device__ __forceinline__ int src_of(int e, const int* __restrict__ ei) {
  return (e < N_EDGES) ? ei[e] : (e - N_EDGES);
}
__device__ __forceinline__ int dst_of(int e, const int* __restrict__ ei) {
  return (e < N_EDGES) ? ei[N_EDGES + e] : (e - N_EDGES);
}
__device__ __forceinline__ float bf2f(unsigned short u) {
  return __uint_as_float(((unsigned int)u) << 16);
}

/* ---------------- CSR build: degree, scan, scatter ---------------- */

__global__ void k_deg(const int* __restrict__ ei, int* __restrict__ deg) {
  int e = blockIdx.x * 256 + threadIdx.x;
  if (e >= E_TOT) return;
  atomicAdd(&deg[dst_of(e, ei)], 1);
}

__global__ void k_scan1(const int* __restrict__ deg, int* __restrict__ part) {
  __shared__ int s[256];
  int t = threadIdx.x;
  int i = blockIdx.x * 256 + t;
  s[t] = (i < N_NODES) ? deg[i] : 0;
  __syncthreads();
  for (int d = 128; d > 0; d >>= 1) {
    if (t < d) s[t] += s[t + d];
    __syncthreads();
  }
  if (t == 0) part[blockIdx.x] = s[0];
}

__global__ void k_scan2(const int* __restrict__ part, int* __restrict__ ppref) {
  if (threadIdx.x == 0) {
    int run = 0;
    for (int i = 0; i < NB; ++i) { ppref[i] = run; run += part[i]; }
  }
}

__global__ void k_scan3(const int* __restrict__ deg, const int* __restrict__ ppref,
                        int* __restrict__ offs, int* __restrict__ cursor) {
  __shared__ int s[256];
  int t = threadIdx.x;
  int i = blockIdx.x * 256 + t;
  int v = (i < N_NODES) ? deg[i] : 0;
  s[t] = v;
  __syncthreads();
  for (int d = 1; d < 256; d <<= 1) {
    int u = (t >= d) ? s[t - d] : 0;
    __syncthreads();
    s[t] += u;
    __syncthreads();
  }
  int excl = s[t] - v;
  if (i < N_NODES) {
    int off = ppref[blockIdx.x] + excl;
    offs[i] = off;
    cursor[i] = off;
  }
}

__global__ void k_scatter(const int* __restrict__ ei, int* __restrict__ cursor,
                          int* __restrict__ sorted) {
  int e = blockIdx.x * 256 + threadIdx.x;
  if (e >= E_TOT) return;
  int d = dst_of(e, ei);
  int pos = atomicAdd(&cursor[d], 1);
  sorted[pos] = e;
}

/* ---- was[k,h] = sum_f W1[k, h*78+f] * a_src1[h*78+f]; same for wad ---- */

__global__ void k_prep(const float* __restrict__ W1, const float* __restrict__ as1,
                       const float* __restrict__ ad1, float* __restrict__ was,
                       float* __restrict__ wad) {
  int i = blockIdx.x * 256 + threadIdx.x;
  if (i >= F_IN * H1) return;
  int k = i / H1, h = i - k * H1;
  const float* wrow = W1 + (size_t)k * D1 + h * 78;
  const float* ar = as1 + h * 78;
  const float* br = ad1 + h * 78;
  float s = 0.f, d = 0.f;
  for (int f = 0; f < 78; ++f) {
    float w = wrow[f];
    s = fmaf(w, ar[f], s);
    d = fmaf(w, br[f], d);
  }
  was[i] = s;  /* layout [k][h], stride H1 */
  wad[i] = d;
}

/* ---- als1[n,h] = x[n,:] . was[:,h] ; ald1 likewise ---- */

__global__ void k_logits1(const float* __restrict__ x, const float* __restrict__ was,
                          const float* __restrict__ wad, float* __restrict__ als,
                          float* __restrict__ ald) {
  int i = blockIdx.x * 256 + threadIdx.x;
  if (i >= N_NODES * H1) return;
  int n = i / H1, h = i - n * H1;
  const float* xr = x + (size_t)n * F_IN;
  float s = 0.f, d = 0.f;
  for (int k = 0; k < F_IN; ++k) {
    float xv = xr[k];
    s = fmaf(xv, was[k * H1 + h], s);
    d = fmaf(xv, wad[k * H1 + h], d);
  }
  als[i] = s;
  ald[i] = d;
}

/* ---------------- per-edge logits, softmax: layer 1 ---------------- */

__global__ void k_edge1(const int* __restrict__ ei, const float* __restrict__ als,
                        const float* __restrict__ ald, float* __restrict__ e1) {
  int i = blockIdx.x * 256 + threadIdx.x;
  if (i >= E_TOT * H1) return;
  int e = i / H1, h = i - e * H1;
  float v = als[src_of(e, ei) * H1 + h] + ald[dst_of(e, ei) * H1 + h];
  e1[i] = (v > 0.f) ? v : NEG_SLOPE * v;
}

__global__ void k_reduce1(const float* __restrict__ e1, const int* __restrict__ sorted,
                          const int* __restrict__ offs, const int* __restrict__ deg,
                          float* __restrict__ m1, float* __restrict__ rd1) {
  int i = blockIdx.x * 256 + threadIdx.x;
  if (i >= N_NODES * H1) return;
  int n = i / H1, h = i - n * H1;
  int o = offs[n], dg = deg[n];
  float m = -1e30f;
  for (int j = 0; j < dg; ++j) m = fmaxf(m, e1[sorted[o + j] * H1 + h]);
  float s = 0.f;
  for (int j = 0; j < dg; ++j) s += __expf(e1[sorted[o + j] * H1 + h] - m);
  m1[i] = m;
  rd1[i] = 1.f / s;
}

__global__ void k_alpha1(const int* __restrict__ ei, float* __restrict__ e1,
                         const float* __restrict__ m1, const float* __restrict__ rd1) {
  int i = blockIdx.x * 256 + threadIdx.x;
  if (i >= E_TOT * H1) return;
  int e = i / H1, h = i - e * H1;
  int d = dst_of(e, ei);
  e1[i] = __expf(e1[i] - m1[d * H1 + h]) * rd1[d * H1 + h];
}

/* ---- fused layer-1 aggregation:
   xagg[n,h,:] = sum_e alpha[e,h] x[src_e,:]   (registers -> LDS)
   out1[n, h*78+f] = ELU( xagg[n,h,:] . W1[:, h*78+f] + b1 )  (bf16) ---- */

__global__ __launch_bounds__(320) void k_agg1f(const float* __restrict__ x,
                                               const float* __restrict__ alpha,
                                               const int* __restrict__ sorted,
                                               const int* __restrict__ offs,
                                               const int* __restrict__ deg,
                                               const int* __restrict__ ei,
                                               const float* __restrict__ W1,
                                               const float* __restrict__ b1,
                                               __hip_bfloat16* __restrict__ out1) {
  __shared__ float xagg[8][H1][80];
  int tid = threadIdx.x;
  int wv = tid >> 6, lane = tid & 63;
  int n0 = blockIdx.x * 8;

  /* phase 1: per-wave node aggregation, accumulators in registers */
  for (int g = wv; g < 8; g += 5) {
    int n = n0 + g;
    int o = offs[n], dg = deg[n];
    float acc[H1], acc2[H1];
    #pragma unroll
    for (int h = 0; h < H1; ++h) { acc[h] = 0.f; acc2[h] = 0.f; }
    for (int j = 0; j < dg; ++j) {
      int e = sorted[o + j];
      int sn = src_of(e, ei);
      const float* xr = x + (size_t)sn * F_IN;
      float xv = xr[lane];
      float xv2 = (lane < F_IN - 64) ? xr[64 + lane] : 0.f;
      const float* ar = alpha + (size_t)e * H1;
      #pragma unroll
      for (int h = 0; h < H1; ++h) {
        float a = ar[h];
        acc[h] = fmaf(a, xv, acc[h]);
        acc2[h] = fmaf(a, xv2, acc2[h]);
      }
    }
    #pragma unroll
    for (int h = 0; h < H1; ++h) {
      xagg[g][h][lane] = acc[h];
      if (lane < 16) xagg[g][h][64 + lane] = (lane < F_IN - 64) ? acc2[h] : 0.f;
    }
  }
  __syncthreads();

  /* phase 2: out1[g, h*78 + j + {0,26,52}] over k=0..77 */
  if (tid < 260) {
    int h = tid / 26, j0 = tid - h * 26;
    int c0 = h * 78 + j0;
    float s[8][3];
    #pragma unroll
    for (int g = 0; g < 8; ++g)
      #pragma unroll
      for (int q = 0; q < 3; ++q) s[g][q] = 0.f;
    for (int k = 0; k < F_IN; ++k) {
      const float* wr = W1 + (size_t)k * D1 + c0;
      float w0 = wr[0], w1 = wr[26], w2 = wr[52];
      #pragma unroll
      for (int g = 0; g < 8; ++g) {
        float xv = xagg[g][h][k];
        s[g][0] = fmaf(xv, w0, s[g][0]);
        s[g][1] = fmaf(xv, w1, s[g][1]);
        s[g][2] = fmaf(xv, w2, s[g][2]);
      }
    }
    #pragma unroll
    for (int q = 0; q < 3; ++q) {
      int c = c0 + q * 26;
      float bv = b1[c];
      #pragma unroll
      for (int g = 0; g < 8; ++g) {
        float v = s[g][q] + bv;
        v = (v > 0.f) ? v : expm1f(v);  /* ELU */
        out1[(size_t)(n0 + g) * D1 + c] = __float2bfloat16(v);
      }
    }
  }
}

/* ---------------- GEMM2: h2[50000,128] = out1(bf16)[50000,780] @ W2 ---------------- */

__global__ __launch_bounds__(256) void k_gemm2(const __hip_bfloat16* __restrict__ A,
                                               const float* __restrict__ W2,
                                               float* __restrict__ C) {
  __shared__ __align__(16) float sA[64][68];
  __shared__ __align__(16) float sB[64][128];
  int m0 = blockIdx.x * 64;
  int tid = threadIdx.x;
  int cg = tid & 15, rg = tid >> 4;
  float acc[4][8];
  #pragma unroll
  for (int r = 0; r < 4; ++r)
    #pragma unroll
    for (int j = 0; j < 8; ++j) acc[r][j] = 0.f;

  for (int k0 = 0; k0 < D1; k0 += 64) {
    for (int t = tid; t < 1024; t += 256) {
      int m = t >> 4, kq = t & 15;
      int gm = m0 + m, gk = k0 + kq * 4;
      float4 v = make_float4(0.f, 0.f, 0.f, 0.f);
      if (gm < N_NODES && gk < D1) {
        ushort4 u = *reinterpret_cast<const ushort4*>(&A[(size_t)gm * D1 + gk]);
        v.x = bf2f(u.x); v.y = bf2f(u.y); v.z = bf2f(u.z); v.w = bf2f(u.w);
      }
      *reinterpret_cast<float4*>(&sA[m][kq * 4]) = v;
    }
    for (int t = tid; t < 2048; t += 256) {
      int k = t >> 5, cq = t & 31;
      int gk = k0 + k;
      float4 v = make_float4(0.f, 0.f, 0.f, 0.f);
      if (gk < D1)
        v = *reinterpret_cast<const float4*>(&W2[(size_t)gk * F_OUT + cq * 4]);
      *reinterpret_cast<float4*>(&sB[k][cq * 4]) = v;
    }
    __syncthreads();
    #pragma unroll 4
    for (int k = 0; k < 64; ++k) {
      float a0 = sA[rg * 4 + 0][k];
      float a1 = sA[rg * 4 + 1][k];
      float a2 = sA[rg * 4 + 2][k];
      float a3 = sA[rg * 4 + 3][k];
      float4 b0 = *reinterpret_cast<const float4*>(&sB[k][cg * 8]);
      float4 b1v = *reinterpret_cast<const float4*>(&sB[k][cg * 8 + 4]);
      float bb[8] = {b0.x, b0.y, b0.z, b0.w, b1v.x, b1v.y, b1v.z, b1v.w};
      #pragma unroll
      for (int j = 0; j < 8; ++j) {
        acc[0][j] = fmaf(a0, bb[j], acc[0][j]);
        acc[1][j] = fmaf(a1, bb[j], acc[1][j]);
        acc[2][j] = fmaf(a2, bb[j], acc[2][j]);
        acc[3][j] = fmaf(a3, bb[j], acc[3][j]);
      }
    }
    __syncthreads();
  }
  #pragma unroll
  for (int r = 0; r < 4; ++r) {
    int gm = m0 + rg * 4 + r;
    if (gm < N_NODES) {
      float4 v0 = make_float4(acc[r][0], acc[r][1], acc[r][2], acc[r][3]);
      float4 v1 = make_float4(acc[r][4], acc[r][5], acc[r][6], acc[r][7]);
      *reinterpret_cast<float4*>(&C[(size_t)gm * F_OUT + cg * 8]) = v0;
      *reinterpret_cast<float4*>(&C[(size_t)gm * F_OUT + cg * 8 + 4]) = v1;
    }
  }
}

/* ---------------- layer 2 attention ---------------- */

__global__ __launch_bounds__(64) void k_al2(const float* __restrict__ h2,
                                            const float* __restrict__ asrc,
                                            const float* __restrict__ adst,
                                            float* __restrict__ als,
                                            float* __restrict__ ald) {
  int n = blockIdx.x, lane = threadIdx.x;
  const float* hp = h2 + (size_t)n * F_OUT;
  float h0 = hp[lane], h64 = hp[64 + lane];
  float s = h0 * asrc[lane] + h64 * asrc[64 + lane];
  float d = h0 * adst[lane] + h64 * adst[64 + lane];
  #pragma unroll
  for (int off = 32; off > 0; off >>= 1) {
    s += __shfl_down(s, off);
    d += __shfl_down(d, off);
  }
  if (lane == 0) { als[n] = s; ald[n] = d; }
}

__global__ void k_edge2(const int* __restrict__ ei, const float* __restrict__ als,
                        const float* __restrict__ ald, float* __restrict__ e2) {
  int e = blockIdx.x * 256 + threadIdx.x;
  if (e >= E_TOT) return;
  float v = als[src_of(e, ei)] + ald[dst_of(e, ei)];
  e2[e] = (v > 0.f) ? v : NEG_SLOPE * v;
}

__global__ void k_reduce2(const float* __restrict__ e2, const int* __restrict__ sorted,
                          const int* __restrict__ offs, const int* __restrict__ deg,
                          float* __restrict__ m2, float* __restrict__ rd2) {
  int n = blockIdx.x * 256 + threadIdx.x;
  if (n >= N_NODES) return;
  int o = offs[n], dg = deg[n];
  float m = -1e30f;
  for (int j = 0; j < dg; ++j) m = fmaxf(m, e2[sorted[o + j]]);
  float s = 0.f;
  for (int j = 0; j < dg; ++j) s += __expf(e2[sorted[o + j]] - m);
  m2[n] = m;
  rd2[n] = 1.f / s;
}

__global__ void k_alpha2(const int* __restrict__ ei, float* __restrict__ e2,
                         const float* __restrict__ m2, const float* __restrict__ rd2) {
  int e = blockIdx.x * 256 + threadIdx.x;
  if (e >= E_TOT) return;
  int d = dst_of(e, ei);
  e2[e] = __expf(e2[e] - m2[d]) * rd2[d];
}

__global__ __launch_bounds__(128) void k_agg2(const float* __restrict__ h2,
                                              const float* __restrict__ alpha,
                                              const int* __restrict__ sorted,
                                              const int* __restrict__ offs,
                                              const int* __restrict__ deg,
                                              const int* __restrict__ ei,
                                              const float* __restrict__ b2,
                                              float* __restrict__ out2) {
  int n = blockIdx.x;
  int tid = threadIdx.x;
  int o = offs[n], dg = deg[n];
  __shared__ int sE[128], sS[128];
  float acc = 0.f;
  for (int base = 0; base < dg; base += 128) {
    int cnt = min(128, dg - base);
    __syncthreads();
    if (tid < cnt) {
      int e = sorted[o + base + tid];
      sE[tid] = e;
      sS[tid] = src_of(e, ei);
    }
    __syncthreads();
    for (int i = 0; i < cnt; ++i)
      acc = fmaf(alpha[sE[i]], h2[(size_t)sS[i] * F_OUT + tid], acc);
  }
  float v = acc + b2[tid];
  out2[(size_t)n * F_OUT + tid] = fmaxf(v, 0.f);
}

/* ---------------- pool + fc ---------------- */

__global__ void k_pool(const float* __restrict__ out2, const int* __restrict__ batch,
                       unsigned int* __restrict__ g) {
  int i = blockIdx.x * 256 + threadIdx.x;
  if (i >= N_NODES * F_OUT) return;
  int n = i >> 7, f = i & 127;
  float v = out2[i];
  atomicMax(&g[batch[n] * F_OUT + f], __float_as_uint(v));
}

__global__ __launch_bounds__(128) void k_fc(const float* __restrict__ g,
                                            const float* __restrict__ fc_w,
                                            const float* __restrict__ fc_b,
                                            float* __restrict__ out) {
  int b = blockIdx.x, c = threadIdx.x;
  const float* gr = g + (size_t)b * F_OUT;
  float acc = 0.f;
  for (int k = 0; k < F_OUT; ++k) acc = fmaf(gr[k], fc_w[k * F_OUT + c], acc);
  float v = acc + fc_b[c];
  out[(size_t)b * F_OUT + c] = fmaxf(v, 0.f);
}

/* ---------------- launch ---------------- */

extern "C" void kernel_launch(void* const* d_in, const int* in_sizes, int n_in,
                              void* d_out, int out_size, void* d_ws, size_t ws_size,
                              hipStream_t stream) {
  const float* x      = (const float*)d_in[0];
  const int*   ei     = (const int*)  d_in[1];
  const int*   batch  = (const int*)  d_in[2];
  const float* W1     = (const float*)d_in[3];
  const float* a_src1 = (const float*)d_in[4];
  const float* a_dst1 = (const float*)d_in[5];
  const float* b1     = (const float*)d_in[6];
  const float* W2     = (const float*)d_in[7];
  const float* a_src2 = (const float*)d_in[8];
  const float* a_dst2 = (const float*)d_in[9];
  const float* b2     = (const float*)d_in[10];
  const float* fc_w   = (const float*)d_in[11];
  const float* fc_b   = (const float*)d_in[12];
  float* out = (float*)d_out;

  float* ws = (float*)d_ws;
  /* total footprint: 38,902,448 floats = 155.6 MB */
  __hip_bfloat16* out1 = (__hip_bfloat16*)ws;        /* 39,000,000 bf16 = 19.5M floats */
  float* h2   = ws + 19500000;            /* 6,400,000 */
  float* out2 = ws + 25900000;            /* 6,400,000 */
  float* e1   = ws + 32300000;            /* 3,500,000 */
  float* als1 = ws + 35800000;            /*   500,000 */
  float* ald1 = ws + 36300000;
  float* m1   = ws + 36800000;
  float* rd1  = ws + 37300000;
  float* e2   = ws + 37800000;            /*   350,000 */
  float* als2 = ws + 38150000;
  float* ald2 = ws + 38200000;
  float* m2   = ws + 38250000;
  float* rd2  = ws + 38300000;
  float* g    = ws + 38350000;            /*    32,768 */
  float* was  = ws + 38400000;            /*       780 */
  float* wad  = ws + 38401000;            /*       780 */
  int* ib     = (int*)(ws + 38402000);
  int* deg    = ib;                        /*  50,000 */
  int* offs   = ib + 50000;
  int* cursor = ib + 100000;
  int* sorted = ib + 150000;               /* 350,000 */
  int* part   = ib + 500000;               /* 196 */
  int* ppref  = ib + 500224;               /* 196 */

  /* CSR build */
  hipMemsetAsync(deg, 0, N_NODES * sizeof(int), stream);
  k_deg<<<(E_TOT + 255) / 256, 256, 0, stream>>>(ei, deg);
  k_scan1<<<NB, 256, 0, stream>>>(deg, part);
  k_scan2<<<1, 64, 0, stream>>>(part, ppref);
  k_scan3<<<NB, 256, 0, stream>>>(deg, ppref, offs, cursor);
  k_scatter<<<(E_TOT + 255) / 256, 256, 0, stream>>>(ei, cursor, sorted);

  /* layer 1 */
  k_prep<<<4, 256, 0, stream>>>(W1, a_src1, a_dst1, was, wad);
  k_logits1<<<(N_NODES * H1 + 255) / 256, 256, 0, stream>>>(x, was, wad, als1, ald1);
  k_edge1<<<(E_TOT * H1 + 255) / 256, 256, 0, stream>>>(ei, als1, ald1, e1);
  k_reduce1<<<(N_NODES * H1 + 255) / 256, 256, 0, stream>>>(e1, sorted, offs, deg, m1, rd1);
  k_alpha1<<<(E_TOT * H1 + 255) / 256, 256, 0, stream>>>(ei, e1, m1, rd1);
  k_agg1f<<<N_NODES / 8, 320, 0, stream>>>(x, e1, sorted, offs, deg, ei, W1, b1, out1);

  /* layer 2 */
  k_gemm2<<<(N_NODES + 63) / 64, 256, 0, stream>>>(out1, W2, h2);
  k_al2<<<N_NODES, 64, 0, stream>>>(h2, a_src2, a_dst2, als2, ald2);
  k_edge2<<<(E_TOT + 255) / 256, 256, 0, stream>>>(ei, als2, ald2, e2);
  k_reduce2<<<(N_NODES + 255) / 256, 256, 0, stream>>>(e2, sorted, offs, deg, m2, rd2);
  k_alpha2<<<(E_TOT + 255) / 256, 256, 0, stream>>>(ei, e2, m2, rd2);
  k_agg2<<<N_NODES, 128, 0, stream>>>(h2, e2, sorted, offs, deg, ei, b2, out2);

  /* pool + fc */
  hipMemsetAsync(g, 0, N_GRAPHS * F_OUT * sizeof(float), stream);
  k_pool<<<(N_NODES * F_OUT + 255) / 256, 256, 0, stream>>>(out2, batch, (unsigned int*)g);
  k_fc<<<N_GRAPHS, F_OUT, 0, stream>>>(g, fc_w, fc_b, out);
}